// Round 5
// baseline (3254.394 us; speedup 1.0000x reference)
//
#include <hip/hip_runtime.h>
#include <hip/hip_bf16.h>

#define N_SENT 2048
#define S_LEN  64
#define QL     16
#define NQ     128
#define NB     32
#define DD     256
#define VOCAB  100032

using bf16x8 = __attribute__((ext_vector_type(8))) short;
using f32x4  = __attribute__((ext_vector_type(4))) float;

// ---------------- workspace layout (float offsets) ----------------
#define WS_X   0
#define WS_WX  (WS_X  + N_SENT*DD)
#define WS_Q   (WS_WX + N_SENT*DD)
#define WS_KS  (WS_Q  + NQ*DD)
#define WS_KVB (WS_KS + N_SENT*NB)
#define WS_HF  (WS_KVB+ NB*DD)
#define WS_Z   (WS_HF + NB*DD)
#define WS_BF  (WS_Z  + NQ*DD)        // 131072 ushort = 65536 float slots

// ---------------- encoders ----------------
__global__ __launch_bounds__(256) void encode_story(
    const int* __restrict__ inp, const float* __restrict__ emb,
    const float* __restrict__ f, float* __restrict__ X)
{
    const int t = blockIdx.x, d = threadIdx.x;
    __shared__ int idx[S_LEN];
    if (d < S_LEN) idx[d] = inp[t*S_LEN + d];
    __syncthreads();
    float acc = 0.f;
#pragma unroll 4
    for (int p = 0; p < S_LEN; ++p)
        acc += emb[(size_t)idx[p]*DD + d] * f[p*DD + d];
    X[t*DD + d] = acc;
}

__global__ __launch_bounds__(256) void encode_query(
    const int* __restrict__ qry, const float* __restrict__ emb,
    const float* __restrict__ f, float* __restrict__ Q)
{
    const int i = blockIdx.x, d = threadIdx.x;
    __shared__ int idx[QL];
    if (d < QL) idx[d] = qry[i*QL + d];
    __syncthreads();
    float acc = 0.f;
#pragma unroll
    for (int p = 0; p < QL; ++p)
        acc += emb[(size_t)idx[p]*DD + d] * f[p*DD + d];
    Q[i*DD + d] = acc;
}

// ---------------- WX / KS ----------------
__global__ __launch_bounds__(256) void wx_ks(
    const float* __restrict__ X, const float* __restrict__ W,
    const float* __restrict__ keys, float* __restrict__ WX, float* __restrict__ KS)
{
    const int t = blockIdx.x, n = threadIdx.x;
    __shared__ float xs[DD];
    xs[n] = X[t*DD + n];
    __syncthreads();
    float acc = 0.f;
    const float4* wr = (const float4*)&W[n*DD];
    const float4* xp = (const float4*)xs;
#pragma unroll 8
    for (int k4 = 0; k4 < 64; ++k4) {
        float4 w = wr[k4], x = xp[k4];
        acc += w.x*x.x + w.y*x.y + w.z*x.z + w.w*x.w;
    }
    WX[t*DD + n] = acc;
    if (n < NB) {
        float a2 = 0.f;
        const float4* kr = (const float4*)&keys[n*DD];
#pragma unroll 8
        for (int k4 = 0; k4 < 64; ++k4) {
            float4 kv = kr[k4], x = xp[k4];
            a2 += kv.x*x.x + kv.y*x.y + kv.z*x.z + kv.w*x.w;
        }
        KS[t*NB + n] = a2;
    }
}

// ---------------- KVB ----------------
__global__ __launch_bounds__(256) void kvb_kernel(
    const float* __restrict__ keys, const float* __restrict__ V,
    const float* __restrict__ bias, float* __restrict__ KVB)
{
    const int jj = blockIdx.x, n = threadIdx.x;
    __shared__ float ks[DD];
    ks[n] = keys[jj*DD + n];
    __syncthreads();
    float acc = bias[n];
    const float4* vr = (const float4*)&V[n*DD];
    const float4* kp = (const float4*)ks;
#pragma unroll 8
    for (int k4 = 0; k4 < 64; ++k4) {
        float4 v = vr[k4], k = kp[k4];
        acc += v.x*k.x + v.y*k.y + v.z*k.z + v.w*k.w;
    }
    KVB[jj*DD + n] = acc;
}

// ---------------- prep: U -> bf16 hi/lo MFMA B-fragments ----------------
// frag f = (pass*16 + ntile)*8 + ktile; lane l: B[k][n] = U[n][k] with
// n = ntile*16 + (l&15), k = ktile*32 + (l>>4)*8 + i.  hi = truncate-to-bf16,
// lo = truncate-to-bf16(U - hi).
__global__ __launch_bounds__(64) void prep_ufrag(
    const float* __restrict__ U, ushort* __restrict__ Bf)
{
    const int f = blockIdx.x;         // 0..255
    const int l = threadIdx.x;        // 0..63
    const int kt = f & 7, nt = (f >> 3) & 15, p = f >> 7;
    const int n  = nt*16 + (l & 15);
    const int kb = kt*32 + (l >> 4)*8;
    ushort out[8];
#pragma unroll
    for (int i = 0; i < 8; ++i) {
        float v = U[n*DD + kb + i];
        unsigned b  = __float_as_uint(v);
        unsigned hi = b & 0xFFFF0000u;
        if (p == 0) out[i] = (ushort)(hi >> 16);
        else {
            float lo = v - __uint_as_float(hi);
            out[i] = (ushort)(__float_as_uint(lo) >> 16);
        }
    }
    *(uint4*)&Bf[((size_t)f*64 + l)*8] = *(const uint4*)out;
}

// ---------------- sequential scan: MFMA bf16 hi/lo path ----------------
// 512 thr = 8 waves; wave w owns output N-tiles {2w, 2w+1}. U fragments
// (32 bf16x8 = 128 regs) live in VGPR/AGPR — MFMA reads either natively.
// A-operand rows: 0 = hhi, 1 = hlo (rows 2-15 zero). Two passes B=Uhi,Ulo:
// y = D0.row0 + D0.row1 + D1.row0. Deferred normalization; 2 barriers/step.
__global__ __launch_bounds__(512)
__attribute__((amdgpu_waves_per_eu(2, 2)))
void scan_kernel(
    const float* __restrict__ X,  const float* __restrict__ WX,
    const float* __restrict__ KS, const float* __restrict__ KVB,
    const ushort* __restrict__ Bf, const float* __restrict__ h0,
    const float* __restrict__ a_mem_p, float* __restrict__ Hf,
    float* __restrict__ HfOut)
{
    const int j    = blockIdx.x;
    const int tid  = threadIdx.x;
    const int w    = tid >> 6;       // wave 0..7
    const int lane = tid & 63;
    const int c    = lane & 15;      // A-row / D-col
    const int g    = lane >> 4;      // k-group

    __shared__ __align__(16) ushort h_hi[DD];
    __shared__ __align__(16) ushort h_lo[DD];
    __shared__ float gred[8];
    __shared__ float nred[8];
    __shared__ float pad[20480];     // 80 KB -> 1 workgroup/CU
    ((volatile float*)pad)[tid] = 0.f;

    // ---- load U fragments (persist whole kernel; AGPR-safe for MFMA) ----
    bf16x8 b00[8], b01[8], b10[8], b11[8];   // [ntile2][pass][kt]
#pragma unroll
    for (int kt = 0; kt < 8; ++kt) {
        b00[kt] = *(const bf16x8*)&Bf[(((size_t)(0*16 + 2*w  )*8 + kt)*64 + lane)*8];
        b01[kt] = *(const bf16x8*)&Bf[(((size_t)(1*16 + 2*w  )*8 + kt)*64 + lane)*8];
        b10[kt] = *(const bf16x8*)&Bf[(((size_t)(0*16 + 2*w+1)*8 + kt)*64 + lane)*8];
        b11[kt] = *(const bf16x8*)&Bf[(((size_t)(1*16 + 2*w+1)*8 + kt)*64 + lane)*8];
    }

    const bool owner = (lane < 16);
    const int n0 = (2*w)*16 + c;
    const int n1 = (2*w + 1)*16 + c;
    float hreg0 = 0.f, hreg1 = 0.f, kvb0 = 0.f, kvb1 = 0.f;
    if (owner) {
        hreg0 = h0[j*DD + n0];  hreg1 = h0[j*DD + n1];
        kvb0  = KVB[j*DD + n0]; kvb1  = KVB[j*DD + n1];
        unsigned bb0 = __float_as_uint(hreg0), hh0 = bb0 & 0xFFFF0000u;
        h_hi[n0] = (ushort)(hh0 >> 16);
        h_lo[n0] = (ushort)(__float_as_uint(hreg0 - __uint_as_float(hh0)) >> 16);
        unsigned bb1 = __float_as_uint(hreg1), hh1 = bb1 & 0xFFFF0000u;
        h_hi[n1] = (ushort)(hh1 >> 16);
        h_lo[n1] = (ushort)(__float_as_uint(hreg1 - __uint_as_float(hh1)) >> 16);
    }
    if (tid < 8) nred[tid] = 0.125f;     // sum = 1 -> inv = 1 on first step
    const float am = *a_mem_p;

    // prefetch t=0 operands
    float s0 = 0.f, s1 = 0.f, wx0 = 0.f, wx1 = 0.f;
    if (owner) { s0 = X[n0]; s1 = X[n1]; wx0 = WX[n0]; wx1 = WX[n1]; }
    float ksv = KS[j];
    __syncthreads();

    const bf16x8 azero = {0,0,0,0,0,0,0,0};

    for (int t = 0; t < N_SENT; ++t) {
        const float inv = rsqrtf(nred[0]+nred[1]+nred[2]+nred[3]
                               + nred[4]+nred[5]+nred[6]+nred[7]);

        // A fragments from h hi/lo (rows 0/1; other rows zero)
        bf16x8 a[8];
        if (c < 2) {
            const ushort* hp = (c == 0) ? h_hi : h_lo;
#pragma unroll
            for (int kt = 0; kt < 8; ++kt)
                a[kt] = *(const bf16x8*)&hp[kt*32 + g*8];
        } else {
#pragma unroll
            for (int kt = 0; kt < 8; ++kt) a[kt] = azero;
        }

        // gate-dot partial on prev h-hat (f32, exact path)
        float gp = owner ? (hreg0*s0 + hreg1*s1) : 0.f;
        gp += __shfl_xor(gp, 1); gp += __shfl_xor(gp, 2);
        gp += __shfl_xor(gp, 4); gp += __shfl_xor(gp, 8);
        if (lane == 0) gred[w] = gp;

        // MFMA: 4 chains x 8 K-tiles
        f32x4 acc00 = {0.f,0.f,0.f,0.f}, acc01 = {0.f,0.f,0.f,0.f};
        f32x4 acc10 = {0.f,0.f,0.f,0.f}, acc11 = {0.f,0.f,0.f,0.f};
#pragma unroll
        for (int kt = 0; kt < 8; ++kt) {
            acc00 = __builtin_amdgcn_mfma_f32_16x16x32_bf16(a[kt], b00[kt], acc00, 0, 0, 0);
            acc01 = __builtin_amdgcn_mfma_f32_16x16x32_bf16(a[kt], b01[kt], acc01, 0, 0, 0);
            acc10 = __builtin_amdgcn_mfma_f32_16x16x32_bf16(a[kt], b10[kt], acc10, 0, 0, 0);
            acc11 = __builtin_amdgcn_mfma_f32_16x16x32_bf16(a[kt], b11[kt], acc11, 0, 0, 0);
        }

        // prefetch t+1 operands
        const int tn = (t + 1 < N_SENT) ? t + 1 : t;
        float s0n = 0.f, s1n = 0.f, wx0n = 0.f, wx1n = 0.f;
        if (owner) {
            s0n  = X[tn*DD + n0];  s1n  = X[tn*DD + n1];
            wx0n = WX[tn*DD + n0]; wx1n = WX[tn*DD + n1];
        }
        const float ksn = KS[tn*NB + j];

        __syncthreads();             // B1: gred ready; all A-reads done
        float np = 0.f;
        if (owner) {
            float gz = inv*(gred[0]+gred[1]+gred[2]+gred[3]
                          + gred[4]+gred[5]+gred[6]+gred[7]) + ksv;
            float gate = 1.f / (1.f + expf(-gz));
            float y0 = inv*(acc00.x + acc00.y + acc01.x) + kvb0 + wx0;
            float y1 = inv*(acc10.x + acc10.y + acc11.x) + kvb1 + wx1;
            float hs0 = (y0 >= 0.f) ? y0 : am*y0;
            float hs1 = (y1 >= 0.f) ? y1 : am*y1;
            float hn0 = inv*hreg0 + gate*hs0;
            float hn1 = inv*hreg1 + gate*hs1;
            hreg0 = hn0; hreg1 = hn1;
            np = hn0*hn0 + hn1*hn1;
            unsigned bb0 = __float_as_uint(hn0), hh0 = bb0 & 0xFFFF0000u;
            h_hi[n0] = (ushort)(hh0 >> 16);
            h_lo[n0] = (ushort)(__float_as_uint(hn0 - __uint_as_float(hh0)) >> 16);
            unsigned bb1 = __float_as_uint(hn1), hh1 = bb1 & 0xFFFF0000u;
            h_hi[n1] = (ushort)(hh1 >> 16);
            h_lo[n1] = (ushort)(__float_as_uint(hn1 - __uint_as_float(hh1)) >> 16);
        }
        np += __shfl_xor(np, 1); np += __shfl_xor(np, 2);
        np += __shfl_xor(np, 4); np += __shfl_xor(np, 8);
        if (lane == 0) nred[w] = np;
        s0 = s0n; s1 = s1n; wx0 = wx0n; wx1 = wx1n; ksv = ksn;
        __syncthreads();             // B2: h hi/lo + nred ready
    }
    if (owner) {
        const float inv = rsqrtf(nred[0]+nred[1]+nred[2]+nred[3]
                               + nred[4]+nred[5]+nred[6]+nred[7]);
        Hf[j*DD + n0]    = hreg0*inv;  Hf[j*DD + n1]    = hreg1*inv;
        HfOut[j*DD + n0] = hreg0*inv;  HfOut[j*DD + n1] = hreg1*inv;
    }
}

// ---------------- output module small part ----------------
__global__ __launch_bounds__(256) void out_small(
    const float* __restrict__ Qe, const float* __restrict__ Hfm,
    const float* __restrict__ Hw, const float* __restrict__ Hb,
    const float* __restrict__ a_out_p, float* __restrict__ Z)
{
    const int i = blockIdx.x, d = threadIdx.x;
    __shared__ float hsh[NB*DD];
    __shared__ float red[4];
    __shared__ float csh[NB];
    __shared__ float ush[DD];
#pragma unroll
    for (int jj = 0; jj < NB; ++jj) hsh[jj*DD + d] = Hfm[jj*DD + d];
    const float qd = Qe[i*DD + d];
    __syncthreads();
    float s2 = 0.f;
#pragma unroll
    for (int jj = 0; jj < NB; ++jj) { float h = hsh[jj*DD + d]; s2 += h*h; }
    for (int jj = 0; jj < NB; ++jj) {
        float p = qd * hsh[jj*DD + d];
        float m = p;
#pragma unroll
        for (int o = 32; o; o >>= 1) m = fmaxf(m, __shfl_xor(m, o));
        if ((d & 63) == 0) red[d >> 6] = m;
        __syncthreads();
        m = fmaxf(fmaxf(red[0], red[1]), fmaxf(red[2], red[3]));
        __syncthreads();
        float e = expf(p - m);
#pragma unroll
        for (int o = 32; o; o >>= 1) e += __shfl_xor(e, o);
        if ((d & 63) == 0) red[d >> 6] = e;
        __syncthreads();
        if (d == 0) csh[jj] = m + logf(red[0] + red[1] + red[2] + red[3]);
        __syncthreads();
    }
    float u = qd * s2;
#pragma unroll
    for (int jj = 0; jj < NB; ++jj) u -= csh[jj] * hsh[jj*DD + d];
    ush[d] = u;
    __syncthreads();
    float acc = qd + Hb[d];
    const float4* hwr = (const float4*)&Hw[d*DD];
    const float4* up  = (const float4*)ush;
#pragma unroll 8
    for (int k4 = 0; k4 < 64; ++k4) {
        float4 w = hwr[k4], uu = up[k4];
        acc += w.x*uu.x + w.y*uu.y + w.z*uu.z + w.w*uu.w;
    }
    const float ao = *a_out_p;
    Z[i*DD + d] = (acc >= 0.f) ? acc : ao * acc;
}

// ---------------- big GEMM: Y = Z @ Rw^T + Rb ----------------
__global__ __launch_bounds__(256) void out_gemm(
    const float* __restrict__ Z, const float* __restrict__ Rw,
    const float* __restrict__ Rb, float* __restrict__ Y)
{
    const int vt  = blockIdx.x * 64;
    const int tid = threadIdx.x;
    __shared__ float rw_sh[64*DD];
    __shared__ float z_sh[64*DD];
#pragma unroll
    for (int it = 0; it < 16; ++it) {
        int f = tid + it*256;
        int row = f >> 6, c = f & 63;
        float4 v = *(const float4*)&Rw[(size_t)(vt + row)*DD + 4*c];
        int u = c ^ ((row >> 2) & 7);
        *(float4*)&rw_sh[row*DD + 4*u] = v;
    }
    const int vg = tid & 15;
    const int ig = tid >> 4;
    const float4 rb4 = *(const float4*)&Rb[vt + vg*4];

    for (int ic = 0; ic < 2; ++ic) {
        const int i0 = ic * 64;
        __syncthreads();
#pragma unroll
        for (int it = 0; it < 16; ++it) {
            int f = tid + it*256;
            int row = f >> 6, c = f & 63;
            float4 v = *(const float4*)&Z[(i0 + row)*DD + 4*c];
            int u = c ^ ((row >> 2) & 7);
            *(float4*)&z_sh[row*DD + 4*u] = v;
        }
        __syncthreads();
        float acc[4][4];
#pragma unroll
        for (int b = 0; b < 4; ++b)
#pragma unroll
            for (int a = 0; a < 4; ++a) acc[b][a] = 0.f;
#pragma unroll 2
        for (int kc = 0; kc < 64; ++kc) {
            float4 ra[4], zb[4];
            const int ur = (kc ^ (vg & 7)) * 4;
            const int uz = (kc ^ (ig & 7)) * 4;
#pragma unroll
            for (int a = 0; a < 4; ++a) ra[a] = *(const float4*)&rw_sh[(vg*4 + a)*DD + ur];
#pragma unroll
            for (int b = 0; b < 4; ++b) zb[b] = *(const float4*)&z_sh[(ig*4 + b)*DD + uz];
#pragma unroll
            for (int b = 0; b < 4; ++b)
#pragma unroll
                for (int a = 0; a < 4; ++a)
                    acc[b][a] += zb[b].x*ra[a].x + zb[b].y*ra[a].y
                               + zb[b].z*ra[a].z + zb[b].w*ra[a].w;
        }
#pragma unroll
        for (int b = 0; b < 4; ++b) {
            int i = i0 + ig*4 + b;
            float4 o;
            o.x = acc[b][0] + rb4.x; o.y = acc[b][1] + rb4.y;
            o.z = acc[b][2] + rb4.z; o.w = acc[b][3] + rb4.w;
            *(float4*)&Y[(size_t)i*VOCAB + vt + vg*4] = o;
        }
    }
}

extern "C" void kernel_launch(void* const* d_in, const int* in_sizes, int n_in,
                              void* d_out, int out_size, void* d_ws, size_t ws_size,
                              hipStream_t stream)
{
    (void)in_sizes; (void)n_in; (void)out_size; (void)ws_size;
    const int*   inputs  = (const int*)  d_in[0];
    const int*   query   = (const int*)  d_in[1];
    const float* h0      = (const float*)d_in[2];
    const float* emb     = (const float*)d_in[3];
    const float* f_story = (const float*)d_in[4];
    const float* f_query = (const float*)d_in[5];
    const float* U       = (const float*)d_in[6];
    const float* V       = (const float*)d_in[7];
    const float* W       = (const float*)d_in[8];
    const float* bias    = (const float*)d_in[9];
    const float* keys    = (const float*)d_in[10];
    const float* a_mem   = (const float*)d_in[11];
    const float* Hw      = (const float*)d_in[12];
    const float* Hb      = (const float*)d_in[13];
    const float* Rw      = (const float*)d_in[14];
    const float* Rb      = (const float*)d_in[15];
    const float* a_out   = (const float*)d_in[16];

    float* ws  = (float*)d_ws;
    float* X   = ws + WS_X;
    float* WX  = ws + WS_WX;
    float* Qe  = ws + WS_Q;
    float* KS  = ws + WS_KS;
    float* KVB = ws + WS_KVB;
    float* Hf  = ws + WS_HF;
    float* Z   = ws + WS_Z;
    ushort* Bf = (ushort*)(ws + WS_BF);

    float* Y     = (float*)d_out;
    float* HfOut = Y + (size_t)NQ * VOCAB;

    encode_story<<<N_SENT, 256, 0, stream>>>(inputs, emb, f_story, X);
    encode_query<<<NQ,    256, 0, stream>>>(query,  emb, f_query, Qe);
    wx_ks      <<<N_SENT, 256, 0, stream>>>(X, W, keys, WX, KS);
    kvb_kernel <<<NB,     256, 0, stream>>>(keys, V, bias, KVB);
    prep_ufrag <<<256,     64, 0, stream>>>(U, Bf);
    scan_kernel<<<NB,     512, 0, stream>>>(X, WX, KS, KVB, Bf, h0, a_mem, Hf, HfOut);
    out_small  <<<NQ,     256, 0, stream>>>(Qe, Hf, Hw, Hb, a_out, Z);
    out_gemm   <<<VOCAB/64, 256, 0, stream>>>(Z, Rw, Rb, Y);
}

// Round 6
// 2643.537 us; speedup vs baseline: 1.2311x; 1.2311x over previous
//
#include <hip/hip_runtime.h>
#include <hip/hip_bf16.h>

#define N_SENT 2048
#define S_LEN  64
#define QL     16
#define NQ     128
#define NB     32
#define DD     256
#define VOCAB  100032

using bf16x8 = __attribute__((ext_vector_type(8))) short;
using f32x4  = __attribute__((ext_vector_type(4))) float;

// ---------------- workspace layout (float offsets) ----------------
#define WS_X   0
#define WS_WX  (WS_X  + N_SENT*DD)
#define WS_Q   (WS_WX + N_SENT*DD)
#define WS_KS  (WS_Q  + NQ*DD)
#define WS_KVB (WS_KS + N_SENT*NB)
#define WS_HF  (WS_KVB+ NB*DD)
#define WS_Z   (WS_HF + NB*DD)
#define WS_BF  (WS_Z  + NQ*DD)        // 131072 ushort = 65536 float slots

// ---------------- encoders ----------------
__global__ __launch_bounds__(256) void encode_story(
    const int* __restrict__ inp, const float* __restrict__ emb,
    const float* __restrict__ f, float* __restrict__ X)
{
    const int t = blockIdx.x, d = threadIdx.x;
    __shared__ int idx[S_LEN];
    if (d < S_LEN) idx[d] = inp[t*S_LEN + d];
    __syncthreads();
    float acc = 0.f;
#pragma unroll 4
    for (int p = 0; p < S_LEN; ++p)
        acc += emb[(size_t)idx[p]*DD + d] * f[p*DD + d];
    X[t*DD + d] = acc;
}

__global__ __launch_bounds__(256) void encode_query(
    const int* __restrict__ qry, const float* __restrict__ emb,
    const float* __restrict__ f, float* __restrict__ Q)
{
    const int i = blockIdx.x, d = threadIdx.x;
    __shared__ int idx[QL];
    if (d < QL) idx[d] = qry[i*QL + d];
    __syncthreads();
    float acc = 0.f;
#pragma unroll
    for (int p = 0; p < QL; ++p)
        acc += emb[(size_t)idx[p]*DD + d] * f[p*DD + d];
    Q[i*DD + d] = acc;
}

// ---------------- WX / KS ----------------
__global__ __launch_bounds__(256) void wx_ks(
    const float* __restrict__ X, const float* __restrict__ W,
    const float* __restrict__ keys, float* __restrict__ WX, float* __restrict__ KS)
{
    const int t = blockIdx.x, n = threadIdx.x;
    __shared__ float xs[DD];
    xs[n] = X[t*DD + n];
    __syncthreads();
    float acc = 0.f;
    const float4* wr = (const float4*)&W[n*DD];
    const float4* xp = (const float4*)xs;
#pragma unroll 8
    for (int k4 = 0; k4 < 64; ++k4) {
        float4 w = wr[k4], x = xp[k4];
        acc += w.x*x.x + w.y*x.y + w.z*x.z + w.w*x.w;
    }
    WX[t*DD + n] = acc;
    if (n < NB) {
        float a2 = 0.f;
        const float4* kr = (const float4*)&keys[n*DD];
#pragma unroll 8
        for (int k4 = 0; k4 < 64; ++k4) {
            float4 kv = kr[k4], x = xp[k4];
            a2 += kv.x*x.x + kv.y*x.y + kv.z*x.z + kv.w*x.w;
        }
        KS[t*NB + n] = a2;
    }
}

// ---------------- KVB ----------------
__global__ __launch_bounds__(256) void kvb_kernel(
    const float* __restrict__ keys, const float* __restrict__ V,
    const float* __restrict__ bias, float* __restrict__ KVB)
{
    const int jj = blockIdx.x, n = threadIdx.x;
    __shared__ float ks[DD];
    ks[n] = keys[jj*DD + n];
    __syncthreads();
    float acc = bias[n];
    const float4* vr = (const float4*)&V[n*DD];
    const float4* kp = (const float4*)ks;
#pragma unroll 8
    for (int k4 = 0; k4 < 64; ++k4) {
        float4 v = vr[k4], k = kp[k4];
        acc += v.x*k.x + v.y*k.y + v.z*k.z + v.w*k.w;
    }
    KVB[jj*DD + n] = acc;
}

// ---------------- prep: U -> bf16 hi/lo MFMA B-fragments ----------------
__global__ __launch_bounds__(64) void prep_ufrag(
    const float* __restrict__ U, ushort* __restrict__ Bf)
{
    const int f = blockIdx.x;         // 0..255
    const int l = threadIdx.x;        // 0..63
    const int kt = f & 7, nt = (f >> 3) & 15, p = f >> 7;
    const int n  = nt*16 + (l & 15);
    const int kb = kt*32 + (l >> 4)*8;
    ushort out[8];
#pragma unroll
    for (int i = 0; i < 8; ++i) {
        float v = U[n*DD + kb + i];
        unsigned b  = __float_as_uint(v);
        unsigned hi = b & 0xFFFF0000u;
        if (p == 0) out[i] = (ushort)(hi >> 16);
        else {
            float lo = v - __uint_as_float(hi);
            out[i] = (ushort)(__float_as_uint(lo) >> 16);
        }
    }
    *(uint4*)&Bf[((size_t)f*64 + l)*8] = *(const uint4*)out;
}

__device__ __forceinline__ void split_hilo(float v, ushort& hi, ushort& lo)
{
    unsigned b = __float_as_uint(v);
    unsigned h = b & 0xFFFF0000u;
    hi = (ushort)(h >> 16);
    lo = (ushort)(__float_as_uint(v - __uint_as_float(h)) >> 16);
}

// ---------------- sequential scan: 1-barrier MFMA step ----------------
// 8 waves; wave w owns output dims [32w, 32w+32) via N-tiles {2w,2w+1}; each
// wave computes FULL K=256 dots (no cross-wave matvec reduction). Cross-wave
// state = h-hat only (double-buffered bf16 hi/lo in LDS). Gate dot + norm are
// computed REDUNDANTLY per wave from LDS h-hat (64 lanes x 4 dims, 6 shfl_xor)
// -> no owner-diverged LDS reductions, ONE barrier per step. X/WX staged in
// double-buffered LDS (issue loads at step start, ds_write at step end).
__global__ __launch_bounds__(512)
__attribute__((amdgpu_waves_per_eu(2, 2)))
void scan_kernel(
    const float* __restrict__ X,  const float* __restrict__ WX,
    const float* __restrict__ KS, const float* __restrict__ KVB,
    const ushort* __restrict__ Bf, const float* __restrict__ h0,
    const float* __restrict__ a_mem_p, float* __restrict__ Hf,
    float* __restrict__ HfOut)
{
    const int j    = blockIdx.x;
    const int tid  = threadIdx.x;
    const int w    = tid >> 6;       // wave 0..7
    const int lane = tid & 63;
    const int c    = lane & 15;      // A-row / D-col
    const int g    = lane >> 4;      // k-group

    __shared__ __align__(16) ushort h_hi[2][DD];
    __shared__ __align__(16) ushort h_lo[2][DD];
    __shared__ __align__(16) float  xbuf[2][DD];
    __shared__ __align__(16) float  wxbuf[2][DD];
    __shared__ float pad[21504];     // 84 KB -> 1 workgroup/CU
    ((volatile float*)pad)[tid] = 0.f;

    // ---- U fragments (persist whole kernel; AGPR-friendly for MFMA) ----
    bf16x8 b00[8], b01[8], b10[8], b11[8];
#pragma unroll
    for (int kt = 0; kt < 8; ++kt) {
        b00[kt] = *(const bf16x8*)&Bf[(((size_t)(0*16 + 2*w  )*8 + kt)*64 + lane)*8];
        b01[kt] = *(const bf16x8*)&Bf[(((size_t)(1*16 + 2*w  )*8 + kt)*64 + lane)*8];
        b10[kt] = *(const bf16x8*)&Bf[(((size_t)(0*16 + 2*w+1)*8 + kt)*64 + lane)*8];
        b11[kt] = *(const bf16x8*)&Bf[(((size_t)(1*16 + 2*w+1)*8 + kt)*64 + lane)*8];
    }

    const bool owner = (lane < 16);
    const int n0 = 32*w + c;
    const int n1 = n0 + 16;
    float hreg0 = 0.f, hreg1 = 0.f, kvb0 = 0.f, kvb1 = 0.f;
    if (owner) {
        hreg0 = h0[j*DD + n0];  hreg1 = h0[j*DD + n1];
        kvb0  = KVB[j*DD + n0]; kvb1  = KVB[j*DD + n1];
        ushort hh, hl;
        split_hilo(hreg0, hh, hl); h_hi[0][n0] = hh; h_lo[0][n0] = hl;
        split_hilo(hreg1, hh, hl); h_hi[0][n1] = hh; h_lo[0][n1] = hl;
    }
    const float am = *a_mem_p;

    // stage t=0 X/WX into buffer 0
    {
        float v = (tid < 256) ? X[tid] : WX[tid - 256];
        if (tid < 256) xbuf[0][tid] = v; else wxbuf[0][tid - 256] = v;
    }
    float ksv = KS[j];
    __syncthreads();

    bf16x8 a[8];
#pragma unroll
    for (int kt = 0; kt < 8; ++kt) a[kt] = (bf16x8){0,0,0,0,0,0,0,0};

    int cur = 0;
    for (int t = 0; t < N_SENT; ++t) {
        const int nxt = cur ^ 1;

        // ---- phase 1: LDS reads (A-frags + f32 reconstruct + wx) ----
        if (c < 2) {
            const ushort* hp = (c == 0) ? h_hi[cur] : h_lo[cur];
#pragma unroll
            for (int kt = 0; kt < 8; ++kt)
                a[kt] = *(const bf16x8*)&hp[kt*32 + g*8];
        }
        uint2 uh = *(const uint2*)&h_hi[cur][lane*4];
        uint2 ul = *(const uint2*)&h_lo[cur][lane*4];
        float4 xv = *(const float4*)&xbuf[cur][lane*4];
        float hv0 = __uint_as_float((uh.x & 0xFFFFu) << 16) + __uint_as_float((ul.x & 0xFFFFu) << 16);
        float hv1 = __uint_as_float(uh.x & 0xFFFF0000u)     + __uint_as_float(ul.x & 0xFFFF0000u);
        float hv2 = __uint_as_float((uh.y & 0xFFFFu) << 16) + __uint_as_float((ul.y & 0xFFFFu) << 16);
        float hv3 = __uint_as_float(uh.y & 0xFFFF0000u)     + __uint_as_float(ul.y & 0xFFFF0000u);
        float wx0 = 0.f, wx1 = 0.f;
        if (owner) { wx0 = wxbuf[cur][n0]; wx1 = wxbuf[cur][n1]; }

        // ---- phase 2: issue staging loads for t+1 ----
        const int tn = (t + 1 < N_SENT) ? t + 1 : t;
        float stv = (tid < 256) ? X[tn*DD + tid] : WX[tn*DD + tid - 256];
        float ksn = KS[tn*NB + j];

        // ---- phase 3: redundant in-wave reductions (norm + gate) ----
        float ns = hv0*hv0 + hv1*hv1 + hv2*hv2 + hv3*hv3;
        float gs = hv0*xv.x + hv1*xv.y + hv2*xv.z + hv3*xv.w;
#pragma unroll
        for (int o = 1; o <= 32; o <<= 1) {
            ns += __shfl_xor(ns, o);
            gs += __shfl_xor(gs, o);
        }
        const float inv  = rsqrtf(ns);
        const float gz   = inv * gs + ksv;
        const float gate = 1.f / (1.f + expf(-gz));

        // ---- phase 4: MFMAs (4 independent chains x 8 K-tiles) ----
        f32x4 acc00 = {0.f,0.f,0.f,0.f}, acc01 = {0.f,0.f,0.f,0.f};
        f32x4 acc10 = {0.f,0.f,0.f,0.f}, acc11 = {0.f,0.f,0.f,0.f};
#pragma unroll
        for (int kt = 0; kt < 8; ++kt) {
            acc00 = __builtin_amdgcn_mfma_f32_16x16x32_bf16(a[kt], b00[kt], acc00, 0, 0, 0);
            acc01 = __builtin_amdgcn_mfma_f32_16x16x32_bf16(a[kt], b01[kt], acc01, 0, 0, 0);
            acc10 = __builtin_amdgcn_mfma_f32_16x16x32_bf16(a[kt], b10[kt], acc10, 0, 0, 0);
            acc11 = __builtin_amdgcn_mfma_f32_16x16x32_bf16(a[kt], b11[kt], acc11, 0, 0, 0);
        }

        // ---- phase 5: epilogue (owner lanes) ----
        if (owner) {
            float y0 = inv*(acc00.x + acc00.y + acc01.x) + kvb0 + wx0;
            float y1 = inv*(acc10.x + acc10.y + acc11.x) + kvb1 + wx1;
            float hs0 = (y0 >= 0.f) ? y0 : am*y0;
            float hs1 = (y1 >= 0.f) ? y1 : am*y1;
            float hn0 = inv*hreg0 + gate*hs0;
            float hn1 = inv*hreg1 + gate*hs1;
            hreg0 = hn0; hreg1 = hn1;
            ushort hh, hl;
            split_hilo(hn0, hh, hl); h_hi[nxt][n0] = hh; h_lo[nxt][n0] = hl;
            split_hilo(hn1, hh, hl); h_hi[nxt][n1] = hh; h_lo[nxt][n1] = hl;
        }

        // ---- phase 6: write staged X/WX for t+1 ----
        if (tid < 256) xbuf[nxt][tid] = stv; else wxbuf[nxt][tid - 256] = stv;
        ksv = ksn;
        cur = nxt;
        __syncthreads();             // single barrier per step
    }

    // final normalization (redundant per-wave norm of final h-hat)
    {
        uint2 uh = *(const uint2*)&h_hi[cur][lane*4];
        uint2 ul = *(const uint2*)&h_lo[cur][lane*4];
        float hv0 = __uint_as_float((uh.x & 0xFFFFu) << 16) + __uint_as_float((ul.x & 0xFFFFu) << 16);
        float hv1 = __uint_as_float(uh.x & 0xFFFF0000u)     + __uint_as_float(ul.x & 0xFFFF0000u);
        float hv2 = __uint_as_float((uh.y & 0xFFFFu) << 16) + __uint_as_float((ul.y & 0xFFFFu) << 16);
        float hv3 = __uint_as_float(uh.y & 0xFFFF0000u)     + __uint_as_float(ul.y & 0xFFFF0000u);
        float ns = hv0*hv0 + hv1*hv1 + hv2*hv2 + hv3*hv3;
#pragma unroll
        for (int o = 1; o <= 32; o <<= 1) ns += __shfl_xor(ns, o);
        const float inv = rsqrtf(ns);
        if (owner) {
            Hf[j*DD + n0]    = hreg0*inv;  Hf[j*DD + n1]    = hreg1*inv;
            HfOut[j*DD + n0] = hreg0*inv;  HfOut[j*DD + n1] = hreg1*inv;
        }
    }
}

// ---------------- output module small part ----------------
__global__ __launch_bounds__(256) void out_small(
    const float* __restrict__ Qe, const float* __restrict__ Hfm,
    const float* __restrict__ Hw, const float* __restrict__ Hb,
    const float* __restrict__ a_out_p, float* __restrict__ Z)
{
    const int i = blockIdx.x, d = threadIdx.x;
    __shared__ float hsh[NB*DD];
    __shared__ float red[4];
    __shared__ float csh[NB];
    __shared__ float ush[DD];
#pragma unroll
    for (int jj = 0; jj < NB; ++jj) hsh[jj*DD + d] = Hfm[jj*DD + d];
    const float qd = Qe[i*DD + d];
    __syncthreads();
    float s2 = 0.f;
#pragma unroll
    for (int jj = 0; jj < NB; ++jj) { float h = hsh[jj*DD + d]; s2 += h*h; }
    for (int jj = 0; jj < NB; ++jj) {
        float p = qd * hsh[jj*DD + d];
        float m = p;
#pragma unroll
        for (int o = 32; o; o >>= 1) m = fmaxf(m, __shfl_xor(m, o));
        if ((d & 63) == 0) red[d >> 6] = m;
        __syncthreads();
        m = fmaxf(fmaxf(red[0], red[1]), fmaxf(red[2], red[3]));
        __syncthreads();
        float e = expf(p - m);
#pragma unroll
        for (int o = 32; o; o >>= 1) e += __shfl_xor(e, o);
        if ((d & 63) == 0) red[d >> 6] = e;
        __syncthreads();
        if (d == 0) csh[jj] = m + logf(red[0] + red[1] + red[2] + red[3]);
        __syncthreads();
    }
    float u = qd * s2;
#pragma unroll
    for (int jj = 0; jj < NB; ++jj) u -= csh[jj] * hsh[jj*DD + d];
    ush[d] = u;
    __syncthreads();
    float acc = qd + Hb[d];
    const float4* hwr = (const float4*)&Hw[d*DD];
    const float4* up  = (const float4*)ush;
#pragma unroll 8
    for (int k4 = 0; k4 < 64; ++k4) {
        float4 w = hwr[k4], uu = up[k4];
        acc += w.x*uu.x + w.y*uu.y + w.z*uu.z + w.w*uu.w;
    }
    const float ao = *a_out_p;
    Z[i*DD + d] = (acc >= 0.f) ? acc : ao * acc;
}

// ---------------- big GEMM: Y = Z @ Rw^T + Rb ----------------
__global__ __launch_bounds__(256) void out_gemm(
    const float* __restrict__ Z, const float* __restrict__ Rw,
    const float* __restrict__ Rb, float* __restrict__ Y)
{
    const int vt  = blockIdx.x * 64;
    const int tid = threadIdx.x;
    __shared__ float rw_sh[64*DD];
    __shared__ float z_sh[64*DD];
#pragma unroll
    for (int it = 0; it < 16; ++it) {
        int f = tid + it*256;
        int row = f >> 6, c = f & 63;
        float4 v = *(const float4*)&Rw[(size_t)(vt + row)*DD + 4*c];
        int u = c ^ ((row >> 2) & 7);
        *(float4*)&rw_sh[row*DD + 4*u] = v;
    }
    const int vg = tid & 15;
    const int ig = tid >> 4;
    const float4 rb4 = *(const float4*)&Rb[vt + vg*4];

    for (int ic = 0; ic < 2; ++ic) {
        const int i0 = ic * 64;
        __syncthreads();
#pragma unroll
        for (int it = 0; it < 16; ++it) {
            int f = tid + it*256;
            int row = f >> 6, c = f & 63;
            float4 v = *(const float4*)&Z[(i0 + row)*DD + 4*c];
            int u = c ^ ((row >> 2) & 7);
            *(float4*)&z_sh[row*DD + 4*u] = v;
        }
        __syncthreads();
        float acc[4][4];
#pragma unroll
        for (int b = 0; b < 4; ++b)
#pragma unroll
            for (int a = 0; a < 4; ++a) acc[b][a] = 0.f;
#pragma unroll 2
        for (int kc = 0; kc < 64; ++kc) {
            float4 ra[4], zb[4];
            const int ur = (kc ^ (vg & 7)) * 4;
            const int uz = (kc ^ (ig & 7)) * 4;
#pragma unroll
            for (int a = 0; a < 4; ++a) ra[a] = *(const float4*)&rw_sh[(vg*4 + a)*DD + ur];
#pragma unroll
            for (int b = 0; b < 4; ++b) zb[b] = *(const float4*)&z_sh[(ig*4 + b)*DD + uz];
#pragma unroll
            for (int b = 0; b < 4; ++b)
#pragma unroll
                for (int a = 0; a < 4; ++a)
                    acc[b][a] += zb[b].x*ra[a].x + zb[b].y*ra[a].y
                               + zb[b].z*ra[a].z + zb[b].w*ra[a].w;
        }
#pragma unroll
        for (int b = 0; b < 4; ++b) {
            int i = i0 + ig*4 + b;
            float4 o;
            o.x = acc[b][0] + rb4.x; o.y = acc[b][1] + rb4.y;
            o.z = acc[b][2] + rb4.z; o.w = acc[b][3] + rb4.w;
            *(float4*)&Y[(size_t)i*VOCAB + vt + vg*4] = o;
        }
    }
}

extern "C" void kernel_launch(void* const* d_in, const int* in_sizes, int n_in,
                              void* d_out, int out_size, void* d_ws, size_t ws_size,
                              hipStream_t stream)
{
    (void)in_sizes; (void)n_in; (void)out_size; (void)ws_size;
    const int*   inputs  = (const int*)  d_in[0];
    const int*   query   = (const int*)  d_in[1];
    const float* h0      = (const float*)d_in[2];
    const float* emb     = (const float*)d_in[3];
    const float* f_story = (const float*)d_in[4];
    const float* f_query = (const float*)d_in[5];
    const float* U       = (const float*)d_in[6];
    const float* V       = (const float*)d_in[7];
    const float* W       = (const float*)d_in[8];
    const float* bias    = (const float*)d_in[9];
    const float* keys    = (const float*)d_in[10];
    const float* a_mem   = (const float*)d_in[11];
    const float* Hw      = (const float*)d_in[12];
    const float* Hb      = (const float*)d_in[13];
    const float* Rw      = (const float*)d_in[14];
    const float* Rb      = (const float*)d_in[15];
    const float* a_out   = (const float*)d_in[16];

    float* ws  = (float*)d_ws;
    float* X   = ws + WS_X;
    float* WX  = ws + WS_WX;
    float* Qe  = ws + WS_Q;
    float* KS  = ws + WS_KS;
    float* KVB = ws + WS_KVB;
    float* Hf  = ws + WS_HF;
    float* Z   = ws + WS_Z;
    ushort* Bf = (ushort*)(ws + WS_BF);

    float* Y     = (float*)d_out;
    float* HfOut = Y + (size_t)NQ * VOCAB;

    encode_story<<<N_SENT, 256, 0, stream>>>(inputs, emb, f_story, X);
    encode_query<<<NQ,    256, 0, stream>>>(query,  emb, f_query, Qe);
    wx_ks      <<<N_SENT, 256, 0, stream>>>(X, W, keys, WX, KS);
    kvb_kernel <<<NB,     256, 0, stream>>>(keys, V, bias, KVB);
    prep_ufrag <<<256,     64, 0, stream>>>(U, Bf);
    scan_kernel<<<NB,     512, 0, stream>>>(X, WX, KS, KVB, Bf, h0, a_mem, Hf, HfOut);
    out_small  <<<NQ,     256, 0, stream>>>(Qe, Hf, Hw, Hb, a_out, Z);
    out_gemm   <<<VOCAB/64, 256, 0, stream>>>(Z, Rw, Rb, Y);
}